// Round 3
// baseline (1892.326 us; speedup 1.0000x reference)
//
#include <hip/hip_runtime.h>
#include <hip/hip_bf16.h>
#include <float.h>

// Problem constants
#define BB   128      // bs*t
#define CCH  256      // z channels
#define EMB_ 256      // embedding dim
#define HW   256      // h*w
#define NPIX 32768    // BB*HW
#define VOC  4096

// ---------------------------------------------------------------- K0a: c_sq
__global__ __launch_bounds__(256) void k_csq(const float* __restrict__ cb,
                                             float* __restrict__ csq) {
    int v = blockIdx.x * 256 + threadIdx.x;   // grid 16
    const float4* row = (const float4*)(cb + v * EMB_);
    float s = 0.f;
#pragma unroll 8
    for (int q = 0; q < 64; ++q) {
        float4 a = row[q];
        s = fmaf(a.x, a.x, fmaf(a.y, a.y, fmaf(a.z, a.z, fmaf(a.w, a.w, s))));
    }
    csq[v] = s;
}

// ------------------------------------------- K0b: postcode = post_b + W@cb^T
__global__ __launch_bounds__(256) void k_postcode(const float* __restrict__ cb,
                                                  const float* __restrict__ post_w,
                                                  const float* __restrict__ post_b,
                                                  float* __restrict__ postcode) {
    __shared__ float cbs[16][EMB_];           // 16 codebook rows, 16 KB
    int v0 = blockIdx.x * 16;                 // grid 256
    int c  = threadIdx.x;
#pragma unroll
    for (int r = 0; r < 16; ++r)
        cbs[r][c] = cb[(v0 + r) * EMB_ + c];  // coalesced
    __syncthreads();

    float acc[16];
    float bias = post_b[c];
#pragma unroll
    for (int r = 0; r < 16; ++r) acc[r] = bias;

    const float4* w4p = (const float4*)(post_w + c * EMB_);
    for (int e4 = 0; e4 < 64; ++e4) {
        float4 w4 = w4p[e4];
#pragma unroll
        for (int r = 0; r < 16; ++r) {
            float4 c4 = *(const float4*)&cbs[r][e4 * 4];
            acc[r] = fmaf(w4.x, c4.x, fmaf(w4.y, c4.y,
                     fmaf(w4.z, c4.z, fmaf(w4.w, c4.w, acc[r]))));
        }
    }
#pragma unroll
    for (int r = 0; r < 16; ++r)
        postcode[(v0 + r) * CCH + c] = acc[r];  // coalesced
}

// ---------------------------------------------------- K1: pre-conv -> z_out
// z[b,e,hw] = pre_b[e] + sum_c pre_w[e,c] * (2*x[b,c,hw]-1)
__global__ __launch_bounds__(256) void k_preconv(const float* __restrict__ x,
                                                 const float* __restrict__ pre_w,
                                                 const float* __restrict__ pre_b,
                                                 float* __restrict__ zout) {
    __shared__ float xsT[16][260];            // [p][c], +4 pad kills conflicts
    int b   = blockIdx.x >> 4;                // grid 2048
    int hw0 = (blockIdx.x & 15) * 16;
    int tid = threadIdx.x;
    int cg = tid >> 4, p = tid & 15;
#pragma unroll
    for (int it = 0; it < 16; ++it) {
        int c = it * 16 + cg;
        xsT[p][c] = 2.f * x[b * (CCH * HW) + c * HW + hw0 + p] - 1.f;
    }
    __syncthreads();

    int e = tid;
    float acc[16];
    float bias = pre_b[e];
#pragma unroll
    for (int q = 0; q < 16; ++q) acc[q] = bias;

    const float4* w4p = (const float4*)(pre_w + e * CCH);
    for (int c4 = 0; c4 < 64; ++c4) {
        float4 w4 = w4p[c4];
#pragma unroll
        for (int q = 0; q < 16; ++q) {
            float4 xv = *(const float4*)&xsT[q][c4 * 4];
            acc[q] = fmaf(w4.x, xv.x, fmaf(w4.y, xv.y,
                     fmaf(w4.z, xv.z, fmaf(w4.w, xv.w, acc[q]))));
        }
    }
    float* zo = zout + b * (EMB_ * HW) + e * HW + hw0;
#pragma unroll
    for (int q = 0; q < 4; ++q) {
        float4 s;
        s.x = acc[q * 4 + 0]; s.y = acc[q * 4 + 1];
        s.z = acc[q * 4 + 2]; s.w = acc[q * 4 + 3];
        *(float4*)&zo[q * 4] = s;
    }
}

// --------------------------------- K2: fused distance + argmin -> tokens(f32)
// dist_v = fl( fl(z_sq + c_sq[v]) - 2*dot(z, cb[v]) ), argmin (first index).
// 8x8 register tile: wave tp owns pixels {8tp..8tp+7} (zt reads are
// wave-uniform broadcasts); lane tv owns codes {v0 + 128j + 2tv + s}
// (stride-2 b64 ct reads, <=2-way per 32-lane phase). 64 FMA : 6 LDS per kk.
__global__ __launch_bounds__(256, 3) void k_dist(const float* __restrict__ zout,
                                                 const float* __restrict__ cb,
                                                 const float* __restrict__ csq,
                                                 float* __restrict__ tok_f) {
    __shared__ float zt[256][32];             // [k][pixel] 32 KB, resident
    __shared__ float ct[8][512];              // [kk][code] 16 KB, staged
    __shared__ float zsq_s[32];

    int b   = blockIdx.x >> 3;                // grid 1024
    int hw0 = (blockIdx.x & 7) * 32;
    int tid = threadIdx.x;
    int tv  = tid & 63;                        // code lane (8 codes/tile)
    int tp  = tid >> 6;                        // wave id -> 8 pixels

    const float* zb = zout + b * (EMB_ * HW) + hw0;
    {
        int p  = tid & 31;
        int kg = tid >> 5;                     // 0..7
#pragma unroll
        for (int r = 0; r < 32; ++r) {
            int k = r * 8 + kg;
            zt[k][p] = zb[k * HW + p];         // coalesced 128B rows
        }
    }
    __syncthreads();
    // zsq: serial fmaf chain k=0..255, bit-identical to passing rounds.
    if (tid < 32) {
        float s = 0.f;
        for (int k = 0; k < 256; ++k) { float z = zt[k][tid]; s = fmaf(z, z, s); }
        zsq_s[tid] = s;
    }
    __syncthreads();

    float zsq[8];
#pragma unroll
    for (int i = 0; i < 8; ++i) zsq[i] = zsq_s[tp * 8 + i];

    float best[8]; int bidx[8];
#pragma unroll
    for (int i = 0; i < 8; ++i) { best[i] = FLT_MAX; bidx[i] = 0; }

    // preload first ct chunk (vt=0, kc=0): rows tid and tid+256, k=0..7
    float4 a0, a1, a2, a3;
    {
        const float4* sa = (const float4*)(cb + tid * EMB_);
        a0 = sa[0]; a1 = sa[1];
        const float4* sb = (const float4*)(cb + (256 + tid) * EMB_);
        a2 = sb[0]; a3 = sb[1];
    }

    for (int vt = 0; vt < 8; ++vt) {          // 512 codes per tile
        int v0 = vt * 512;
        float acc[8][8];
#pragma unroll
        for (int i = 0; i < 8; ++i)
#pragma unroll
            for (int j = 0; j < 8; ++j) acc[i][j] = 0.f;

        for (int kc = 0; kc < 32; ++kc) {     // 8-k chunks
            __syncthreads();                  // previous chunk fully consumed
            ct[0][tid] = a0.x; ct[1][tid] = a0.y; ct[2][tid] = a0.z; ct[3][tid] = a0.w;
            ct[4][tid] = a1.x; ct[5][tid] = a1.y; ct[6][tid] = a1.z; ct[7][tid] = a1.w;
            ct[0][tid + 256] = a2.x; ct[1][tid + 256] = a2.y;
            ct[2][tid + 256] = a2.z; ct[3][tid + 256] = a2.w;
            ct[4][tid + 256] = a3.x; ct[5][tid + 256] = a3.y;
            ct[6][tid + 256] = a3.z; ct[7][tid + 256] = a3.w;
            // prefetch NEXT chunk (hidden behind compute)
            int nvt = (kc == 31) ? vt + 1 : vt;
            int nkc = (kc + 1) & 31;
            if (nvt < 8) {
                const float4* sa = (const float4*)(cb + (nvt * 512 + tid) * EMB_ + nkc * 8);
                a0 = sa[0]; a1 = sa[1];
                const float4* sb = (const float4*)(cb + (nvt * 512 + 256 + tid) * EMB_ + nkc * 8);
                a2 = sb[0]; a3 = sb[1];
            }
            __syncthreads();                  // ct visible
            int kbase = kc * 8;
#pragma unroll
            for (int kk = 0; kk < 8; ++kk) {
                int k = kbase + kk;
                float4 zv0 = *(const float4*)&zt[k][8 * tp];
                float4 zv1 = *(const float4*)&zt[k][8 * tp + 4];
                float2 c0 = *(const float2*)&ct[kk][      2 * tv];
                float2 c1 = *(const float2*)&ct[kk][128 + 2 * tv];
                float2 c2 = *(const float2*)&ct[kk][256 + 2 * tv];
                float2 c3 = *(const float2*)&ct[kk][384 + 2 * tv];
                float za[8] = {zv0.x, zv0.y, zv0.z, zv0.w,
                               zv1.x, zv1.y, zv1.z, zv1.w};
                float cc[8] = {c0.x, c0.y, c1.x, c1.y, c2.x, c2.y, c3.x, c3.y};
#pragma unroll
                for (int i = 0; i < 8; ++i)
#pragma unroll
                    for (int j = 0; j < 8; ++j)
                        acc[i][j] = fmaf(za[i], cc[j], acc[i][j]);
            }
        }
        // fold tile into running argmin; per-thread codes ascend in (j,s)
#pragma unroll
        for (int j = 0; j < 4; ++j) {
            int vbase = v0 + j * 128 + 2 * tv;
            float cs0 = csq[vbase];
            float cs1 = csq[vbase + 1];
#pragma unroll
            for (int i = 0; i < 8; ++i) {
                float d0 = (zsq[i] + cs0) - 2.0f * acc[i][2 * j];
                if (d0 < best[i]) { best[i] = d0; bidx[i] = vbase; }
                float d1 = (zsq[i] + cs1) - 2.0f * acc[i][2 * j + 1];
                if (d1 < best[i]) { best[i] = d1; bidx[i] = vbase + 1; }
            }
        }
    }
    // full-wave lexicographic argmin reduction (64 lanes)
#pragma unroll
    for (int off = 32; off >= 1; off >>= 1) {
#pragma unroll
        for (int i = 0; i < 8; ++i) {
            float ob = __shfl_xor(best[i], off, 64);
            int   oi = __shfl_xor(bidx[i], off, 64);
            if (ob < best[i] || (ob == best[i] && oi < bidx[i])) {
                best[i] = ob; bidx[i] = oi;
            }
        }
    }
    if (tv == 0) {
#pragma unroll
        for (int i = 0; i < 8; ++i)
            tok_f[b * HW + hw0 + tp * 8 + i] = (float)bidx[i];
    }
}

// ------------------------- K3: gather zq_out = cb[t], recon = postcode[t]
__global__ __launch_bounds__(256) void k_gather(const float* __restrict__ tok_f,
                                                const float* __restrict__ cb,
                                                const float* __restrict__ postcode,
                                                float* __restrict__ zq_out,
                                                float* __restrict__ recon) {
    int b  = blockIdx.x >> 3;                 // grid 1024
    int e0 = (blockIdx.x & 7) * 32;
    int hw = threadIdx.x;
    int t  = (int)tok_f[b * HW + hw];
    const float* cbr = cb       + t * EMB_;
    const float* pcr = postcode + t * CCH;
    float* zq = zq_out + b * (EMB_ * HW) + hw;
    float* rc = recon  + b * (CCH * HW) + hw;
#pragma unroll
    for (int j = 0; j < 32; ++j) {
        int e = e0 + j;
        zq[e * HW] = cbr[e];                  // stores coalesced across hw
        rc[e * HW] = pcr[e];
    }
}

extern "C" void kernel_launch(void* const* d_in, const int* in_sizes, int n_in,
                              void* d_out, int out_size, void* d_ws, size_t ws_size,
                              hipStream_t stream) {
    const float* x      = (const float*)d_in[0];
    const float* cb     = (const float*)d_in[1];
    const float* pre_w  = (const float*)d_in[2];
    const float* pre_b  = (const float*)d_in[3];
    const float* post_w = (const float*)d_in[4];
    const float* post_b = (const float*)d_in[5];

    float* out    = (float*)d_out;
    float* z_out  = out;                       //  8388608 elems
    float* zq_out = out + 8388608;             //  8388608
    float* recon  = out + 16777216;            //  8388608
    float* tok_f  = out + 25165824;            //    32768

    float* csq      = (float*)d_ws;            // 4096 floats
    float* postcode = csq + VOC;               // 4096*256 floats (4 MB)

    k_csq     <<<  16, 256, 0, stream>>>(cb, csq);
    k_postcode<<< 256, 256, 0, stream>>>(cb, post_w, post_b, postcode);
    k_preconv <<<2048, 256, 0, stream>>>(x, pre_w, pre_b, z_out);
    k_dist    <<<1024, 256, 0, stream>>>(z_out, cb, csq, tok_f);
    k_gather  <<<1024, 256, 0, stream>>>(tok_f, cb, postcode, zq_out, recon);
}

// Round 4
// 1153.998 us; speedup vs baseline: 1.6398x; 1.6398x over previous
//
#include <hip/hip_runtime.h>
#include <hip/hip_bf16.h>
#include <float.h>

// Problem constants
#define BB   128      // bs*t
#define CCH  256      // z channels
#define EMB_ 256      // embedding dim
#define HW   256      // h*w
#define NPIX 32768    // BB*HW
#define VOC  4096

// ---------------------------------------------------------------- K0a: c_sq
__global__ __launch_bounds__(256) void k_csq(const float* __restrict__ cb,
                                             float* __restrict__ csq) {
    int v = blockIdx.x * 256 + threadIdx.x;   // grid 16
    const float4* row = (const float4*)(cb + v * EMB_);
    float s = 0.f;
#pragma unroll 8
    for (int q = 0; q < 64; ++q) {
        float4 a = row[q];
        s = fmaf(a.x, a.x, fmaf(a.y, a.y, fmaf(a.z, a.z, fmaf(a.w, a.w, s))));
    }
    csq[v] = s;
}

// ------------------------------------------- K0b: postcode = post_b + W@cb^T
__global__ __launch_bounds__(256) void k_postcode(const float* __restrict__ cb,
                                                  const float* __restrict__ post_w,
                                                  const float* __restrict__ post_b,
                                                  float* __restrict__ postcode) {
    __shared__ float cbs[16][EMB_];           // 16 codebook rows, 16 KB
    int v0 = blockIdx.x * 16;                 // grid 256
    int c  = threadIdx.x;
#pragma unroll
    for (int r = 0; r < 16; ++r)
        cbs[r][c] = cb[(v0 + r) * EMB_ + c];  // coalesced
    __syncthreads();

    float acc[16];
    float bias = post_b[c];
#pragma unroll
    for (int r = 0; r < 16; ++r) acc[r] = bias;

    const float4* w4p = (const float4*)(post_w + c * EMB_);
    for (int e4 = 0; e4 < 64; ++e4) {
        float4 w4 = w4p[e4];
#pragma unroll
        for (int r = 0; r < 16; ++r) {
            float4 c4 = *(const float4*)&cbs[r][e4 * 4];
            acc[r] = fmaf(w4.x, c4.x, fmaf(w4.y, c4.y,
                     fmaf(w4.z, c4.z, fmaf(w4.w, c4.w, acc[r]))));
        }
    }
#pragma unroll
    for (int r = 0; r < 16; ++r)
        postcode[(v0 + r) * CCH + c] = acc[r];  // coalesced
}

// ---------------------------------------------------- K1: pre-conv -> z_out
// z[b,e,hw] = pre_b[e] + sum_c pre_w[e,c] * (2*x[b,c,hw]-1)
__global__ __launch_bounds__(256) void k_preconv(const float* __restrict__ x,
                                                 const float* __restrict__ pre_w,
                                                 const float* __restrict__ pre_b,
                                                 float* __restrict__ zout) {
    __shared__ float xsT[16][260];            // [p][c], +4 pad kills conflicts
    int b   = blockIdx.x >> 4;                // grid 2048
    int hw0 = (blockIdx.x & 15) * 16;
    int tid = threadIdx.x;
    int cg = tid >> 4, p = tid & 15;
#pragma unroll
    for (int it = 0; it < 16; ++it) {
        int c = it * 16 + cg;
        xsT[p][c] = 2.f * x[b * (CCH * HW) + c * HW + hw0 + p] - 1.f;
    }
    __syncthreads();

    int e = tid;
    float acc[16];
    float bias = pre_b[e];
#pragma unroll
    for (int q = 0; q < 16; ++q) acc[q] = bias;

    const float4* w4p = (const float4*)(pre_w + e * CCH);
    for (int c4 = 0; c4 < 64; ++c4) {
        float4 w4 = w4p[c4];
#pragma unroll
        for (int q = 0; q < 16; ++q) {
            float4 xv = *(const float4*)&xsT[q][c4 * 4];
            acc[q] = fmaf(w4.x, xv.x, fmaf(w4.y, xv.y,
                     fmaf(w4.z, xv.z, fmaf(w4.w, xv.w, acc[q]))));
        }
    }
    float* zo = zout + b * (EMB_ * HW) + e * HW + hw0;
#pragma unroll
    for (int q = 0; q < 4; ++q) {
        float4 s;
        s.x = acc[q * 4 + 0]; s.y = acc[q * 4 + 1];
        s.z = acc[q * 4 + 2]; s.w = acc[q * 4 + 3];
        *(float4*)&zo[q * 4] = s;
    }
}

// --------------------------------- K2: fused distance + argmin -> tokens(f32)
// dist_v = fl( fl(z_sq + c_sq[v]) - 2*dot(z, cb[v]) ), argmin (first index).
// 8x8 register tile: wave tp owns pixels {8tp..8tp+7} (zt reads wave-uniform
// broadcasts); lane tv (0..63) owns codes {v0 + 128j + 2tv + s} (stride-2 b64
// ct reads, <=2-way per phase = free). 64 fmaf : 6 LDS-reads per k-step.
// Accumulators are 64 NAMED scalars (macro-generated): R3's acc[8][8] array
// was partially demoted to scratch under __launch_bounds__(256,3) -> 1.5 GB
// spill traffic. Named scalars + plain bounds keep everything in VGPRs.

#define DECL_ROW(i) \
    float A##i##_0 = 0.f, A##i##_1 = 0.f, A##i##_2 = 0.f, A##i##_3 = 0.f, \
          A##i##_4 = 0.f, A##i##_5 = 0.f, A##i##_6 = 0.f, A##i##_7 = 0.f;

#define FMA_ROW(i) \
    A##i##_0 = fmaf(z##i, c0, A##i##_0); \
    A##i##_1 = fmaf(z##i, c1, A##i##_1); \
    A##i##_2 = fmaf(z##i, c2, A##i##_2); \
    A##i##_3 = fmaf(z##i, c3, A##i##_3); \
    A##i##_4 = fmaf(z##i, c4, A##i##_4); \
    A##i##_5 = fmaf(z##i, c5, A##i##_5); \
    A##i##_6 = fmaf(z##i, c6, A##i##_6); \
    A##i##_7 = fmaf(z##i, c7, A##i##_7);

#define FOLD1(i, ACC, V) \
    { float dd = (zsq_s[tp * 8 + (i)] + csv) - 2.0f * (ACC); \
      if (dd < best[i]) { best[i] = dd; bidx[i] = (V); } }

#define FOLD_COL(SUF, V) \
    { float csv = csq[(V)]; \
      FOLD1(0, A0_##SUF, (V)) FOLD1(1, A1_##SUF, (V)) \
      FOLD1(2, A2_##SUF, (V)) FOLD1(3, A3_##SUF, (V)) \
      FOLD1(4, A4_##SUF, (V)) FOLD1(5, A5_##SUF, (V)) \
      FOLD1(6, A6_##SUF, (V)) FOLD1(7, A7_##SUF, (V)) }

__global__ __launch_bounds__(256) void k_dist(const float* __restrict__ zout,
                                              const float* __restrict__ cb,
                                              const float* __restrict__ csq,
                                              float* __restrict__ tok_f) {
    __shared__ float zt[256][32];             // [k][pixel] 32 KB, resident
    __shared__ float ct[8][512];              // [kk][code] 16 KB, staged
    __shared__ float zsq_s[32];

    int b   = blockIdx.x >> 3;                // grid 1024
    int hw0 = (blockIdx.x & 7) * 32;
    int tid = threadIdx.x;
    int tv  = tid & 63;                        // code lane (8 codes/tile)
    int tp  = tid >> 6;                        // wave id -> 8 pixels

    const float* zb = zout + b * (EMB_ * HW) + hw0;
    {
        int p  = tid & 31;
        int kg = tid >> 5;                     // 0..7
#pragma unroll
        for (int r = 0; r < 32; ++r) {
            int k = r * 8 + kg;
            zt[k][p] = zb[k * HW + p];         // coalesced 128B rows
        }
    }
    __syncthreads();
    // zsq: serial fmaf chain k=0..255, bit-identical to passing rounds.
    if (tid < 32) {
        float s = 0.f;
        for (int k = 0; k < 256; ++k) { float z = zt[k][tid]; s = fmaf(z, z, s); }
        zsq_s[tid] = s;
    }
    __syncthreads();

    float best[8]; int bidx[8];
#pragma unroll
    for (int i = 0; i < 8; ++i) { best[i] = FLT_MAX; bidx[i] = 0; }

    // preload first ct chunk (vt=0, kc=0): rows tid and tid+256, k=0..7
    float4 a0, a1, a2, a3;
    {
        const float4* sa = (const float4*)(cb + tid * EMB_);
        a0 = sa[0]; a1 = sa[1];
        const float4* sb = (const float4*)(cb + (256 + tid) * EMB_);
        a2 = sb[0]; a3 = sb[1];
    }

    for (int vt = 0; vt < 8; ++vt) {          // 512 codes per tile
        int v0 = vt * 512;
        DECL_ROW(0) DECL_ROW(1) DECL_ROW(2) DECL_ROW(3)
        DECL_ROW(4) DECL_ROW(5) DECL_ROW(6) DECL_ROW(7)

        for (int kc = 0; kc < 32; ++kc) {     // 8-k chunks
            __syncthreads();                  // previous chunk fully consumed
            ct[0][tid] = a0.x; ct[1][tid] = a0.y; ct[2][tid] = a0.z; ct[3][tid] = a0.w;
            ct[4][tid] = a1.x; ct[5][tid] = a1.y; ct[6][tid] = a1.z; ct[7][tid] = a1.w;
            ct[0][tid + 256] = a2.x; ct[1][tid + 256] = a2.y;
            ct[2][tid + 256] = a2.z; ct[3][tid + 256] = a2.w;
            ct[4][tid + 256] = a3.x; ct[5][tid + 256] = a3.y;
            ct[6][tid + 256] = a3.z; ct[7][tid + 256] = a3.w;
            // prefetch NEXT chunk (hidden behind compute)
            int nvt = (kc == 31) ? vt + 1 : vt;
            int nkc = (kc + 1) & 31;
            if (nvt < 8) {
                const float4* sa = (const float4*)(cb + (nvt * 512 + tid) * EMB_ + nkc * 8);
                a0 = sa[0]; a1 = sa[1];
                const float4* sb = (const float4*)(cb + (nvt * 512 + 256 + tid) * EMB_ + nkc * 8);
                a2 = sb[0]; a3 = sb[1];
            }
            __syncthreads();                  // ct visible
            int kbase = kc * 8;
#pragma unroll
            for (int kk = 0; kk < 8; ++kk) {
                int k = kbase + kk;
                float4 zA = *(const float4*)&zt[k][8 * tp];
                float4 zB = *(const float4*)&zt[k][8 * tp + 4];
                float2 q0 = *(const float2*)&ct[kk][      2 * tv];
                float2 q1 = *(const float2*)&ct[kk][128 + 2 * tv];
                float2 q2 = *(const float2*)&ct[kk][256 + 2 * tv];
                float2 q3 = *(const float2*)&ct[kk][384 + 2 * tv];
                float z0 = zA.x, z1 = zA.y, z2 = zA.z, z3 = zA.w;
                float z4 = zB.x, z5 = zB.y, z6 = zB.z, z7 = zB.w;
                float c0 = q0.x, c1 = q0.y, c2 = q1.x, c3 = q1.y;
                float c4 = q2.x, c5 = q2.y, c6 = q3.x, c7 = q3.y;
                FMA_ROW(0) FMA_ROW(1) FMA_ROW(2) FMA_ROW(3)
                FMA_ROW(4) FMA_ROW(5) FMA_ROW(6) FMA_ROW(7)
            }
        }
        // fold tile into running argmin, columns in ascending code order
        {
            int vb0 = v0 +       2 * tv;
            int vb1 = v0 + 128 + 2 * tv;
            int vb2 = v0 + 256 + 2 * tv;
            int vb3 = v0 + 384 + 2 * tv;
            FOLD_COL(0, vb0)     FOLD_COL(1, vb0 + 1)
            FOLD_COL(2, vb1)     FOLD_COL(3, vb1 + 1)
            FOLD_COL(4, vb2)     FOLD_COL(5, vb2 + 1)
            FOLD_COL(6, vb3)     FOLD_COL(7, vb3 + 1)
        }
    }
    // full-wave lexicographic argmin reduction (64 lanes)
#pragma unroll
    for (int off = 32; off >= 1; off >>= 1) {
#pragma unroll
        for (int i = 0; i < 8; ++i) {
            float ob = __shfl_xor(best[i], off, 64);
            int   oi = __shfl_xor(bidx[i], off, 64);
            if (ob < best[i] || (ob == best[i] && oi < bidx[i])) {
                best[i] = ob; bidx[i] = oi;
            }
        }
    }
    if (tv == 0) {
#pragma unroll
        for (int i = 0; i < 8; ++i)
            tok_f[b * HW + hw0 + tp * 8 + i] = (float)bidx[i];
    }
}

// ------------------------- K3: gather zq_out = cb[t], recon = postcode[t]
__global__ __launch_bounds__(256) void k_gather(const float* __restrict__ tok_f,
                                                const float* __restrict__ cb,
                                                const float* __restrict__ postcode,
                                                float* __restrict__ zq_out,
                                                float* __restrict__ recon) {
    int b  = blockIdx.x >> 3;                 // grid 1024
    int e0 = (blockIdx.x & 7) * 32;
    int hw = threadIdx.x;
    int t  = (int)tok_f[b * HW + hw];
    const float* cbr = cb       + t * EMB_;
    const float* pcr = postcode + t * CCH;
    float* zq = zq_out + b * (EMB_ * HW) + hw;
    float* rc = recon  + b * (CCH * HW) + hw;
#pragma unroll
    for (int j = 0; j < 32; ++j) {
        int e = e0 + j;
        zq[e * HW] = cbr[e];                  // stores coalesced across hw
        rc[e * HW] = pcr[e];
    }
}

extern "C" void kernel_launch(void* const* d_in, const int* in_sizes, int n_in,
                              void* d_out, int out_size, void* d_ws, size_t ws_size,
                              hipStream_t stream) {
    const float* x      = (const float*)d_in[0];
    const float* cb     = (const float*)d_in[1];
    const float* pre_w  = (const float*)d_in[2];
    const float* pre_b  = (const float*)d_in[3];
    const float* post_w = (const float*)d_in[4];
    const float* post_b = (const float*)d_in[5];

    float* out    = (float*)d_out;
    float* z_out  = out;                       //  8388608 elems
    float* zq_out = out + 8388608;             //  8388608
    float* recon  = out + 16777216;            //  8388608
    float* tok_f  = out + 25165824;            //    32768

    float* csq      = (float*)d_ws;            // 4096 floats
    float* postcode = csq + VOC;               // 4096*256 floats (4 MB)

    k_csq     <<<  16, 256, 0, stream>>>(cb, csq);
    k_postcode<<< 256, 256, 0, stream>>>(cb, post_w, post_b, postcode);
    k_preconv <<<2048, 256, 0, stream>>>(x, pre_w, pre_b, z_out);
    k_dist    <<<1024, 256, 0, stream>>>(z_out, cb, csq, tok_f);
    k_gather  <<<1024, 256, 0, stream>>>(tok_f, cb, postcode, zq_out, recon);
}